// Round 1
// baseline (954.762 us; speedup 1.0000x reference)
//
#include <hip/hip_runtime.h>
#include <hip/hip_bf16.h>
#include <stdint.h>

// Problem constants
#define B_N   2048
#define D_INC 64
#define H_DIM 512
#define D_OUT 64
#define XW    128      // x row width (real 64 | meta 64)
#define KDIM  512      // W_out column count (= H)

typedef __bf16 v8bf  __attribute__((ext_vector_type(8)));
typedef float  f32x4 __attribute__((ext_vector_type(4)));

__device__ __forceinline__ unsigned short f2bf(float f) {
    uint32_t u = __float_as_uint(f);
    u += 0x7FFF + ((u >> 16) & 1);          // round-to-nearest-even
    return (unsigned short)(u >> 16);
}
__device__ __forceinline__ float bf2f(unsigned short h) {
    return __uint_as_float(((uint32_t)h) << 16);
}
__device__ __forceinline__ float elu1(float v) {
    return v > 0.0f ? v : expm1f(v);
}
// Swizzled LDS byte offset for [row][64 bf16] tiles (row stride 128 B).
// XOR bits 4-6 with row&7: spreads 8 consecutive rows across the 32 banks.
__device__ __forceinline__ int swz(int row, int kByte) {
    return row * 128 + (kByte ^ ((row & 7) << 4));
}

// ---------------- K1: h = elu(meta @ W_in^T + b_in), stored bf16 ----------------
__global__ void k_h(const float* __restrict__ x, const float* __restrict__ W_in,
                    const float* __restrict__ b_in, unsigned short* __restrict__ hb) {
    int idx = blockIdx.x * 256 + threadIdx.x;      // b*512 + j
    int b = idx >> 9, j = idx & 511;
    const float4* xm = (const float4*)(x + (size_t)b * XW + D_INC);
    const float4* wr = (const float4*)(W_in + (size_t)j * 64);
    float acc = 0.f;
#pragma unroll
    for (int q = 0; q < 16; ++q) {
        float4 a = xm[q], w = wr[q];
        acc += a.x * w.x + a.y * w.y + a.z * w.z + a.w * w.w;
    }
    acc = elu1(acc + b_in[j]);
    hb[idx] = f2bf(acc);
}

// ---------------- fused block-GEMM --------------------------------------------
// Computes  outAcc[b, n0+n] += sum_{blk in split} scale(b,blk) *
//                              sum_k h[b,k] * W_out[ROWBASE + blk*BLKROWS + n0+n, k]
// scale(b,blk) = blk < NSCALE ? scaleSrc[b*SSTRIDE + blk] : 1.0
// A operand (bf16) generated on the fly: A[b,k] = bf16(scale * h_bf16[b,k]).
// Tile: BM x BN, wave tile 64x64 (4x4 frags of 16x16x32 bf16 MFMA), BK=64.
template<int BM, int BN, int WN, int NBLK_TOT, int NSCALE, int SSTRIDE,
         int BLKROWS, int ROWBASE, int NSPLIT>
__global__ void k_gemm(const unsigned short* __restrict__ hb,
                       const float* __restrict__ Wout,
                       const float* __restrict__ scaleSrc,
                       float* __restrict__ outAcc, int outStride) {
    constexpr int WM = BM / 64;
    constexpr int NT = WM * WN * 64;       // threads
    constexpr int ACH = (BM * 8) / NT;     // A 8-elem chunks per thread
    constexpr int BCH = (BN * 8) / NT;     // B 8-elem chunks per thread

    __shared__ unsigned short As[BM * 64];
    __shared__ unsigned short Bs[BN * 64];

    const int tid = threadIdx.x;
    const int m0 = blockIdx.x * BM;
    const int n0 = blockIdx.y * BN;
    const int s  = blockIdx.z;
    const int blkBeg = (NBLK_TOT * s) / NSPLIT;
    const int blkEnd = (NBLK_TOT * (s + 1)) / NSPLIT;

    const int wid = tid >> 6;
    const int l   = tid & 63;
    const int lr  = l & 15;     // row/col within fragment
    const int lg  = l >> 4;     // k-group
    const int wm  = wid / WN;
    const int wn  = wid % WN;

    f32x4 acc[4][4];
#pragma unroll
    for (int i = 0; i < 4; ++i)
#pragma unroll
        for (int j = 0; j < 4; ++j) acc[i][j] = (f32x4){0.f, 0.f, 0.f, 0.f};

    for (int blk = blkBeg; blk < blkEnd; ++blk) {
        for (int k0 = 0; k0 < KDIM; k0 += 64) {
            // ---- stage A: scaled h chunk ----
#pragma unroll
            for (int q = 0; q < ACH; ++q) {
                int c = q * NT + tid;              // [0, BM*8)
                int row = c >> 3, k8 = c & 7;
                int bRow = m0 + row;
                float sc = (blk < NSCALE) ? scaleSrc[(size_t)bRow * SSTRIDE + blk] : 1.0f;
                const unsigned short* hp = hb + (size_t)bRow * KDIM + k0 + k8 * 8;
                union { uint4 v; unsigned short u[8]; } in, outv;
                in.v = *(const uint4*)hp;
#pragma unroll
                for (int e = 0; e < 8; ++e) outv.u[e] = f2bf(bf2f(in.u[e]) * sc);
                *(uint4*)((char*)As + swz(row, k8 * 16)) = outv.v;
            }
            // ---- stage B: W_out chunk (f32 -> bf16) ----
#pragma unroll
            for (int q = 0; q < BCH; ++q) {
                int c = q * NT + tid;              // [0, BN*8)
                int n = c >> 3, k8 = c & 7;
                size_t wrow = (size_t)ROWBASE + (size_t)blk * BLKROWS + n0 + n;
                const float* wp = Wout + wrow * KDIM + k0 + k8 * 8;
                float4 w0 = *(const float4*)wp;
                float4 w1 = *(const float4*)(wp + 4);
                union { uint4 v; unsigned short u[8]; } o;
                o.u[0] = f2bf(w0.x); o.u[1] = f2bf(w0.y);
                o.u[2] = f2bf(w0.z); o.u[3] = f2bf(w0.w);
                o.u[4] = f2bf(w1.x); o.u[5] = f2bf(w1.y);
                o.u[6] = f2bf(w1.z); o.u[7] = f2bf(w1.w);
                *(uint4*)((char*)Bs + swz(n, k8 * 16)) = o.v;
            }
            __syncthreads();
            // ---- MFMA: 2 k-steps of 32, 4x4 fragments ----
#pragma unroll
            for (int ks = 0; ks < 2; ++ks) {
                v8bf af[4], bf[4];
#pragma unroll
                for (int mi = 0; mi < 4; ++mi)
                    af[mi] = *(const v8bf*)((char*)As + swz(wm * 64 + mi * 16 + lr, ks * 64 + lg * 16));
#pragma unroll
                for (int ni = 0; ni < 4; ++ni)
                    bf[ni] = *(const v8bf*)((char*)Bs + swz(wn * 64 + ni * 16 + lr, ks * 64 + lg * 16));
#pragma unroll
                for (int mi = 0; mi < 4; ++mi)
#pragma unroll
                    for (int ni = 0; ni < 4; ++ni)
                        acc[mi][ni] = __builtin_amdgcn_mfma_f32_16x16x32_bf16(
                            af[mi], bf[ni], acc[mi][ni], 0, 0, 0);
            }
            __syncthreads();
        }
    }
    // ---- epilogue: atomic accumulate f32 partials ----
#pragma unroll
    for (int mi = 0; mi < 4; ++mi)
#pragma unroll
        for (int ni = 0; ni < 4; ++ni)
#pragma unroll
            for (int r = 0; r < 4; ++r) {
                int rowL = wm * 64 + mi * 16 + lg * 4 + r;   // C/D: row=(l>>4)*4+r
                int colL = wn * 64 + ni * 16 + lr;           //      col=l&15
                atomicAdd(outAcc + (size_t)(m0 + rowL) * outStride + n0 + colL,
                          acc[mi][ni][r]);
            }
}

// ---------------- K3: y = elu(ypre + real·b_out[i*512+h'] + b_out[32768+h']) ----
__global__ void k_fin_y(const float* __restrict__ ypre, const float* __restrict__ x,
                        const float* __restrict__ b_out, float* __restrict__ y) {
    int idx = blockIdx.x * 256 + threadIdx.x;   // b*512 + hh
    int b = idx >> 9, hh = idx & 511;
    float acc = ypre[idx] + b_out[32768 + hh];
    const float* xr = x + (size_t)b * XW;       // real part
#pragma unroll 8
    for (int i = 0; i < 64; ++i)
        acc += xr[i] * b_out[i * 512 + hh];
    y[idx] = elu1(acc);
}

// ---------------- K5: out += y·b_out[33280+h'*64+o] + b_out[66048+o] ------------
__global__ void k_fin_out(const float* __restrict__ y, const float* __restrict__ b_out,
                          float* __restrict__ out) {
    int idx = blockIdx.x * 256 + threadIdx.x;   // b*64 + o
    int b = idx >> 6, o = idx & 63;
    float acc = out[idx] + b_out[66048 + o];
    const float* yr = y + (size_t)b * 512;
#pragma unroll 8
    for (int hh = 0; hh < 512; ++hh)
        acc += yr[hh] * b_out[33280 + hh * 64 + o];
    out[idx] = acc;
}

extern "C" void kernel_launch(void* const* d_in, const int* in_sizes, int n_in,
                              void* d_out, int out_size, void* d_ws, size_t ws_size,
                              hipStream_t stream) {
    const float* x     = (const float*)d_in[0];
    const float* W_in  = (const float*)d_in[1];
    const float* b_in  = (const float*)d_in[2];
    const float* W_out = (const float*)d_in[3];
    const float* b_out = (const float*)d_in[4];
    float* out = (float*)d_out;

    char* ws = (char*)d_ws;
    unsigned short* hb = (unsigned short*)ws;            // 2 MB  h in bf16
    float* ypre        = (float*)(ws + (2u << 20));      // 4 MB  y pre-activation acc
    float* yv          = (float*)(ws + (6u << 20));      // 4 MB  y (f32)
    // total ws use: 10 MB

    hipMemsetAsync(ypre, 0, (size_t)B_N * H_DIM * 4, stream);
    hipMemsetAsync(out,  0, (size_t)B_N * D_OUT * 4, stream);

    k_h<<<(B_N * H_DIM) / 256, 256, 0, stream>>>(x, W_in, b_in, hb);

    // Stage 2: y_pre. 65 blocks (i=0..63 scaled by real, i=64 unit = l_in_b rows).
    // Tiles 256x128, 8 waves, grid (8 M-tiles, 4 N-tiles, 8 K-splits).
    k_gemm<256, 128, 2, 65, 64, XW, 512, 0, 8>
        <<<dim3(8, 4, 8), 512, 0, stream>>>(hb, W_out, x, ypre, H_DIM);

    k_fin_y<<<(B_N * H_DIM) / 256, 256, 0, stream>>>(ypre, x, b_out, yv);

    // Stage 3: out. 513 blocks (h'=0..511 scaled by y, block 512 unit = l_out_b rows).
    // Tiles 256x64, 4 waves, grid (8 M-tiles, 1, 64 K-splits).
    k_gemm<256, 64, 1, 513, 512, H_DIM, 64, 33280, 64>
        <<<dim3(8, 1, 64), 256, 0, stream>>>(hb, W_out, yv, out, D_OUT);

    k_fin_out<<<(B_N * D_OUT) / 256, 256, 0, stream>>>(yv, b_out, out);
}

// Round 2
// 310.172 us; speedup vs baseline: 3.0782x; 3.0782x over previous
//
#include <hip/hip_runtime.h>
#include <hip/hip_bf16.h>
#include <stdint.h>

// Problem constants
#define B_N   2048
#define XW    128      // x row width (real 64 | meta 64)
#define KDIM  512      // W_out column count (= H)
#define NROWS_W   66112
#define NROWS_PAD 66560   // padded bf16-W rows (MODE1 last panel overruns to 66304)

typedef __bf16 v8bf  __attribute__((ext_vector_type(8)));
typedef float  f32x4 __attribute__((ext_vector_type(4)));

__device__ __forceinline__ unsigned short f2bf(float f) {
    uint32_t u = __float_as_uint(f);
    u += 0x7FFF + ((u >> 16) & 1);          // round-to-nearest-even
    return (unsigned short)(u >> 16);
}
__device__ __forceinline__ float bf2f(unsigned short h) {
    return __uint_as_float(((uint32_t)h) << 16);
}
__device__ __forceinline__ float elu1(float v) {
    return v > 0.0f ? v : expm1f(v);
}
__device__ __forceinline__ void gload_lds16(const void* g, void* l) {
    __builtin_amdgcn_global_load_lds(
        (const __attribute__((address_space(1))) unsigned int*)g,
        (__attribute__((address_space(3))) unsigned int*)l, 16, 0, 0);
}

// ---------------- K1: h = elu(meta @ W_in^T + b_in), stored bf16 ----------------
__global__ void k_h(const float* __restrict__ x, const float* __restrict__ W_in,
                    const float* __restrict__ b_in, unsigned short* __restrict__ hb) {
    int idx = blockIdx.x * 256 + threadIdx.x;      // b*512 + j
    int b = idx >> 9, j = idx & 511;
    const float4* xm = (const float4*)(x + (size_t)b * XW + 64);
    const float4* wr = (const float4*)(W_in + (size_t)j * 64);
    float acc = 0.f;
#pragma unroll
    for (int q = 0; q < 16; ++q) {
        float4 a = xm[q], w = wr[q];
        acc += a.x * w.x + a.y * w.y + a.z * w.z + a.w * w.w;
    }
    acc = elu1(acc + b_in[j]);
    hb[idx] = f2bf(acc);
}

// ---------------- K-conv: W_out f32 -> bf16 (padded rows zeroed) ---------------
__global__ void k_conv(const float* __restrict__ Wf, unsigned short* __restrict__ Wb) {
    size_t c = (size_t)blockIdx.x * 256 + threadIdx.x;  // 8-elem chunk id
    size_t row = c >> 6; int kk = (int)(c & 63);
    union { uint4 v; unsigned short u[8]; } o;
    o.v = (uint4){0, 0, 0, 0};
    if (row < NROWS_W) {
        const float* wp = Wf + row * KDIM + kk * 8;
        float4 w0 = *(const float4*)wp, w1 = *(const float4*)(wp + 4);
        o.u[0] = f2bf(w0.x); o.u[1] = f2bf(w0.y); o.u[2] = f2bf(w0.z); o.u[3] = f2bf(w0.w);
        o.u[4] = f2bf(w1.x); o.u[5] = f2bf(w1.y); o.u[6] = f2bf(w1.z); o.u[7] = f2bf(w1.w);
    }
    *(uint4*)(Wb + c * 8) = o.v;
}

// ---------------- panel GEMM with scale-in-epilogue ----------------------------
// P[b, c] = sum_k h[b,k] * W[panel_row(p)+c, k]   (pure bf16 MFMA GEMM)
// outAcc[b, outcol(p,c)] += s(b, grp(p,c)) * P[b,c]   (f32 epilogue)
// MODE 0 (y_pre): panels p = half*65 + i (i<=64; i==64 => l_in_b rows, s=1)
//   W rows = i*512 + half*256 + c ; out col = half*256 + c ; s = real[b,i]
// MODE 1 (out):   panels p = 0..128 (p==128 => l_out_b rows, s=1)
//   W rows = 33280 + p*256 + c ; out col = c&63 ; s = y[b, p*4 + (c>>6)]
template<int MODE, bool BF16B>
__global__ __launch_bounds__(512, 2)
void k_pgemm(const unsigned short* __restrict__ hb,
             const unsigned short* __restrict__ Wb,
             const float* __restrict__ Wf,
             const float* __restrict__ scaleSrc,
             float* __restrict__ outAcc) {
    constexpr int NP   = MODE ? 129 : 130;
    constexpr int OUTW = MODE ? 64 : 512;
    constexpr int SCW  = MODE ? 36 : 9;
    constexpr int NSPLIT = 16;

    __shared__ char smem[131072 + 128 * SCW * 4];
    char* As = smem;                       // [128][512B]  (256 k of bf16, swizzled)
    char* Bs = smem + 65536;               // 2 x [256][128B] (64 k, swizzled)
    float* sc = (float*)(smem + 131072);   // [128][SCW]

    const int tid = threadIdx.x;
    const int m0  = blockIdx.x * 128;
    const int s   = blockIdx.y;
    const int pBeg = (NP * s) / NSPLIT;
    const int pEnd = (NP * (s + 1)) / NSPLIT;
    const int halfS = (MODE == 0 && pBeg >= 65) ? 1 : 0;   // uniform per split
    const int iBeg  = pBeg - halfS * 65;                   // MODE0 first i

    const int wid = tid >> 6, l = tid & 63;
    const int lr = l & 15, lg = l >> 4;
    const int wm = wid >> 2, wn = wid & 3;                 // wave grid 2 x 4

    // ---- stage scales into LDS ----
    for (int c = tid; c < 128 * SCW; c += 512) {
        int row = c / SCW, j = c - row * SCW;
        float v = 1.0f;
        if (MODE == 0) {
            int i = iBeg + j;
            if (i < 64) v = scaleSrc[(size_t)(m0 + row) * XW + i];
        } else {
            int g = pBeg * 4 + j;
            if (g < 512) v = scaleSrc[(size_t)(m0 + row) * KDIM + g];
        }
        sc[c] = v;
    }

    // ---- per-thread fragment addresses ----
    int aB[4], aX[4], bB[4], bX[4];
#pragma unroll
    for (int q = 0; q < 4; ++q) {
        int ra = wm * 64 + q * 16 + lr;
        aB[q] = ra * 512; aX[q] = (ra & 7) << 4;
        int rb = wn * 64 + q * 16 + lr;
        bB[q] = rb * 128; bX[q] = (rb & 7) << 4;
    }
    const int lgx = lg * 16;

    f32x4 accP[4][4], accO[4][4];
#pragma unroll
    for (int mi = 0; mi < 4; ++mi)
#pragma unroll
        for (int ni = 0; ni < 4; ++ni) {
            accP[mi][ni] = (f32x4){0.f, 0.f, 0.f, 0.f};
            accO[mi][ni] = (f32x4){0.f, 0.f, 0.f, 0.f};
        }

    for (int kh = 0; kh < 2; ++kh) {
        // ---- stage A half (128 x 256k bf16 = 64KB), swizzled ds_write ----
#pragma unroll
        for (int q = 0; q < 8; ++q) {
            int c = q * 512 + tid;           // [0,4096)
            int row = c >> 5, kk = c & 31;
            uint4 v = *(const uint4*)(hb + (size_t)(m0 + row) * KDIM + kh * 256 + kk * 8);
            *(uint4*)(As + row * 512 + ((kk * 16) ^ ((row & 7) << 4))) = v;
        }
        // ---- B stage helper (as lambda) ----
        auto stageB = [&](int buf, int p, int k0) {
            char* Bbuf = Bs + buf * 32768;
            int wrowBase = (MODE == 0) ? ((p - halfS * 65) * 512 + halfS * 256)
                                       : (33280 + p * 256);
            if (BF16B) {
                int kByte = kh * 512 + k0 * 128;
#pragma unroll
                for (int j = 0; j < 4; ++j) {
                    int rg = wid * 4 + j;
                    int rowLoc = rg * 8 + (l >> 3);
                    size_t src = (size_t)(wrowBase + rowLoc) * 1024 + kByte
                               + (((l & 7) * 16) ^ ((l >> 3) << 4));
                    gload_lds16((const char*)Wb + src, Bbuf + rg * 1024);
                }
            } else {
                int kf = kh * 256 + k0 * 64;
#pragma unroll
                for (int q = 0; q < 4; ++q) {
                    int c = q * 512 + tid;    // [0,2048)
                    int rowLoc = c >> 3, kk = c & 7;
                    int wrow = wrowBase + rowLoc;
                    union { uint4 v; unsigned short u[8]; } o;
                    o.v = (uint4){0, 0, 0, 0};
                    if (wrow < NROWS_W) {
                        const float* wp = Wf + (size_t)wrow * KDIM + kf + kk * 8;
                        float4 w0 = *(const float4*)wp, w1 = *(const float4*)(wp + 4);
                        o.u[0] = f2bf(w0.x); o.u[1] = f2bf(w0.y);
                        o.u[2] = f2bf(w0.z); o.u[3] = f2bf(w0.w);
                        o.u[4] = f2bf(w1.x); o.u[5] = f2bf(w1.y);
                        o.u[6] = f2bf(w1.z); o.u[7] = f2bf(w1.w);
                    }
                    *(uint4*)(Bbuf + rowLoc * 128 + ((kk * 16) ^ ((rowLoc & 7) << 4))) = o.v;
                }
            }
        };

        stageB(0, pBeg, 0);
        __syncthreads();
        int cur = 0;
        for (int p = pBeg; p < pEnd; ++p) {
#pragma unroll
            for (int k0 = 0; k0 < 4; ++k0) {
                bool isLast = (p == pEnd - 1) && (k0 == 3);
                if (!isLast) stageB(cur ^ 1, (k0 == 3) ? p + 1 : p, (k0 + 1) & 3);
                char* Bbuf = Bs + cur * 32768;
#pragma unroll
                for (int ks = 0; ks < 2; ++ks) {
                    v8bf af[4], bf[4];
                    int kk = (ks * 64 + lgx);
#pragma unroll
                    for (int mi = 0; mi < 4; ++mi)
                        af[mi] = *(const v8bf*)(As + aB[mi] + k0 * 128 + (kk ^ aX[mi]));
#pragma unroll
                    for (int ni = 0; ni < 4; ++ni)
                        bf[ni] = *(const v8bf*)(Bbuf + bB[ni] + (kk ^ bX[ni]));
#pragma unroll
                    for (int mi = 0; mi < 4; ++mi)
#pragma unroll
                        for (int ni = 0; ni < 4; ++ni)
                            accP[mi][ni] = __builtin_amdgcn_mfma_f32_16x16x32_bf16(
                                af[mi], bf[ni], accP[mi][ni], 0, 0, 0);
                }
                if (k0 == 3) {
                    // scale-accumulate P into out-acc, reset P
                    int jj = MODE ? ((p - pBeg) * 4 + wn) : (p - pBeg);
#pragma unroll
                    for (int mi = 0; mi < 4; ++mi) {
                        int rb = wm * 64 + mi * 16 + lg * 4;
#pragma unroll
                        for (int r = 0; r < 4; ++r) {
                            float sv = sc[(rb + r) * SCW + jj];
#pragma unroll
                            for (int ni = 0; ni < 4; ++ni)
                                accO[mi][ni][r] += sv * accP[mi][ni][r];
                        }
#pragma unroll
                        for (int ni = 0; ni < 4; ++ni)
                            accP[mi][ni] = (f32x4){0.f, 0.f, 0.f, 0.f};
                    }
                }
                __syncthreads();
                cur ^= 1;
            }
        }
    }
    // ---- epilogue: atomic accumulate ----
#pragma unroll
    for (int mi = 0; mi < 4; ++mi)
#pragma unroll
        for (int ni = 0; ni < 4; ++ni)
#pragma unroll
            for (int r = 0; r < 4; ++r) {
                int row = wm * 64 + mi * 16 + lg * 4 + r;
                int col = MODE ? (ni * 16 + lr) : (halfS * 256 + wn * 64 + ni * 16 + lr);
                atomicAdd(outAcc + (size_t)(m0 + row) * OUTW + col, accO[mi][ni][r]);
            }
}

// ---------------- K3: y = elu(ypre + real·b_out[i*512+h'] + b_out[32768+h']) ----
__global__ void k_fin_y(const float* __restrict__ ypre, const float* __restrict__ x,
                        const float* __restrict__ b_out, float* __restrict__ y) {
    int idx = blockIdx.x * 256 + threadIdx.x;   // b*512 + hh
    int b = idx >> 9, hh = idx & 511;
    float acc = ypre[idx] + b_out[32768 + hh];
    const float* xr = x + (size_t)b * XW;       // real part
#pragma unroll 8
    for (int i = 0; i < 64; ++i)
        acc += xr[i] * b_out[i * 512 + hh];
    y[idx] = elu1(acc);
}

// ---------------- K5: out += y·b_out[33280+h'*64+o] + b_out[66048+o] ------------
__global__ void k_fin_out(const float* __restrict__ y, const float* __restrict__ b_out,
                          float* __restrict__ out) {
    int idx = blockIdx.x * 256 + threadIdx.x;   // b*64 + o
    int b = idx >> 6, o = idx & 63;
    float acc = out[idx] + b_out[66048 + o];
    const float* yr = y + (size_t)b * 512;
#pragma unroll 8
    for (int hh = 0; hh < 512; ++hh)
        acc += yr[hh] * b_out[33280 + hh * 64 + o];
    out[idx] = acc;
}

extern "C" void kernel_launch(void* const* d_in, const int* in_sizes, int n_in,
                              void* d_out, int out_size, void* d_ws, size_t ws_size,
                              hipStream_t stream) {
    const float* x     = (const float*)d_in[0];
    const float* W_in  = (const float*)d_in[1];
    const float* b_in  = (const float*)d_in[2];
    const float* W_out = (const float*)d_in[3];
    const float* b_out = (const float*)d_in[4];
    float* out = (float*)d_out;

    char* ws = (char*)d_ws;
    unsigned short* hb = (unsigned short*)ws;            // 2 MB  h bf16
    float* ypre        = (float*)(ws + (2u << 20));      // 4 MB
    float* yv          = (float*)(ws + (6u << 20));      // 4 MB
    unsigned short* Wb = (unsigned short*)(ws + (10u << 20));  // 68.2 MB bf16 W_out
    const size_t NEED = (10u << 20) + (size_t)NROWS_PAD * KDIM * 2;
    const bool bf16b = ws_size >= NEED;

    hipMemsetAsync(ypre, 0, (size_t)B_N * 512 * 4, stream);
    hipMemsetAsync(out,  0, (size_t)B_N * 64 * 4, stream);

    k_h<<<(B_N * 512) / 256, 256, 0, stream>>>(x, W_in, b_in, hb);

    if (bf16b) {
        k_conv<<<(NROWS_PAD * KDIM / 8) / 256, 256, 0, stream>>>(W_out, Wb);
        k_pgemm<0, true><<<dim3(16, 16), 512, 0, stream>>>(hb, Wb, W_out, x, ypre);
        k_fin_y<<<(B_N * 512) / 256, 256, 0, stream>>>(ypre, x, b_out, yv);
        k_pgemm<1, true><<<dim3(16, 16), 512, 0, stream>>>(hb, Wb, W_out, yv, out);
    } else {
        k_pgemm<0, false><<<dim3(16, 16), 512, 0, stream>>>(hb, Wb, W_out, x, ypre);
        k_fin_y<<<(B_N * 512) / 256, 256, 0, stream>>>(ypre, x, b_out, yv);
        k_pgemm<1, false><<<dim3(16, 16), 512, 0, stream>>>(hb, Wb, W_out, yv, out);
    }
    k_fin_out<<<(B_N * 64) / 256, 256, 0, stream>>>(yv, b_out, out);
}

// Round 3
// 284.419 us; speedup vs baseline: 3.3569x; 1.0905x over previous
//
#include <hip/hip_runtime.h>
#include <hip/hip_bf16.h>
#include <stdint.h>

// Problem constants
#define B_N   2048
#define XW    128      // x row width (real 64 | meta 64)
#define KDIM  512      // W_out column count (= H)
#define NROWS_W   66112
#define NROWS_PAD 66560   // padded bf16-W rows

typedef __bf16 v8bf  __attribute__((ext_vector_type(8)));
typedef float  f32x4 __attribute__((ext_vector_type(4)));

__device__ __forceinline__ unsigned short f2bf(float f) {
    uint32_t u = __float_as_uint(f);
    u += 0x7FFF + ((u >> 16) & 1);          // round-to-nearest-even
    return (unsigned short)(u >> 16);
}
__device__ __forceinline__ float elu1(float v) {
    return v > 0.0f ? v : expm1f(v);
}
__device__ __forceinline__ void gload_lds16(const void* g, void* l) {
    __builtin_amdgcn_global_load_lds(
        (const __attribute__((address_space(1))) unsigned int*)g,
        (__attribute__((address_space(3))) unsigned int*)l, 16, 0, 0);
}

// ---------------- K1: h = elu(meta @ W_in^T + b_in), stored bf16 ----------------
__global__ void k_h(const float* __restrict__ x, const float* __restrict__ W_in,
                    const float* __restrict__ b_in, unsigned short* __restrict__ hb) {
    int idx = blockIdx.x * 256 + threadIdx.x;      // b*512 + j
    int b = idx >> 9, j = idx & 511;
    const float4* xm = (const float4*)(x + (size_t)b * XW + 64);
    const float4* wr = (const float4*)(W_in + (size_t)j * 64);
    float acc = 0.f;
#pragma unroll
    for (int q = 0; q < 16; ++q) {
        float4 a = xm[q], w = wr[q];
        acc += a.x * w.x + a.y * w.y + a.z * w.z + a.w * w.w;
    }
    acc = elu1(acc + b_in[j]);
    hb[idx] = f2bf(acc);
}

// ---------------- K-conv: W_out f32 -> bf16 (padded rows zeroed) ---------------
__global__ void k_conv(const float* __restrict__ Wf, unsigned short* __restrict__ Wb) {
    size_t c = (size_t)blockIdx.x * 256 + threadIdx.x;  // 8-elem chunk id
    size_t row = c >> 6; int kk = (int)(c & 63);
    union { uint4 v; unsigned short u[8]; } o;
    o.v = (uint4){0, 0, 0, 0};
    if (row < NROWS_W) {
        const float* wp = Wf + row * KDIM + kk * 8;
        float4 w0 = *(const float4*)wp, w1 = *(const float4*)(wp + 4);
        o.u[0] = f2bf(w0.x); o.u[1] = f2bf(w0.y); o.u[2] = f2bf(w0.z); o.u[3] = f2bf(w0.w);
        o.u[4] = f2bf(w1.x); o.u[5] = f2bf(w1.y); o.u[6] = f2bf(w1.z); o.u[7] = f2bf(w1.w);
    }
    *(uint4*)(Wb + c * 8) = o.v;
}

// ---------------- panel GEMM, counted-vmcnt pipeline ---------------------------
// P[b,c] = sum_k h[b,k] * W[panelrow(p)+c, k]   (bf16 MFMA, K-quarters of 128)
// outAcc[b, outcol] += s(b, grp) * P    (vector f32 epilogue per (p,kq))
// Block: 128 rows x 128 panel-cols, 256 thr (4 waves, wave-tile 64x64).
// LDS: A quarter [128][256B] + B 2x[128][128B] + scales  = 70-75 KB -> 2 blk/CU.
template<int MODE>
__global__ __launch_bounds__(256, 2)
void k_pgemm(const unsigned short* __restrict__ hb,
             const unsigned short* __restrict__ Wb,
             const float* __restrict__ scaleSrc,
             float* __restrict__ outAcc) {
    constexpr int NP   = MODE ? 129 : 130;
    constexpr int OUTW = MODE ? 64 : 512;
    constexpr int SCW  = MODE ? 18 : 9;

    __shared__ char smem[65536 + SCW * 128 * 4];
    char* As = smem;                      // [128][256B], slot ^= row&7
    char* Bs = smem + 32768;              // 2 x [128][128B], slot ^= row&7
    float* sc = (float*)(smem + 65536);   // transposed: sc[jj*128 + row]

    const int tid = threadIdx.x;
    const int m0  = blockIdx.x * 128;
    const int nh  = blockIdx.y;           // N-half of the 256-row panel
    const int s   = blockIdx.z;
    const int pBeg = (NP * s) >> 4;
    const int pEnd = (NP * (s + 1)) >> 4;
    const int halfS = (MODE == 0 && pBeg >= 65) ? 1 : 0;   // uniform per split
    const int iBeg  = pBeg - halfS * 65;

    const int wid = tid >> 6, l = tid & 63;
    const int lr = l & 15, lg = l >> 4;
    const int wm = wid >> 1, wn = wid & 1;                 // wave grid 2x2

    // ---- stage scales (transposed) ----
    for (int c = tid; c < SCW * 128; c += 256) {
        int jj = c >> 7, row = c & 127;
        float v = 1.0f;
        if (MODE == 0) {
            int i = iBeg + jj;
            if (i < 64) v = scaleSrc[(size_t)(m0 + row) * XW + i];
        } else {
            int g = (pBeg + (jj >> 1)) * 4 + nh * 2 + (jj & 1);
            if (g < 512) v = scaleSrc[(size_t)(m0 + row) * KDIM + g];
        }
        sc[c] = v;
    }

    // ---- per-thread fragment bases ----
    int aB[4], aX[4], bB[4], bX[4];
#pragma unroll
    for (int q = 0; q < 4; ++q) {
        int ra = wm * 64 + q * 16 + lr;
        aB[q] = ra * 256; aX[q] = ra & 7;
        int rb = wn * 64 + q * 16 + lr;
        bB[q] = rb * 128; bX[q] = rb & 7;
    }

    f32x4 accP[4][4], accO[4][4];
#pragma unroll
    for (int mi = 0; mi < 4; ++mi)
#pragma unroll
        for (int ni = 0; ni < 4; ++ni) {
            accP[mi][ni] = (f32x4){0.f, 0.f, 0.f, 0.f};
            accO[mi][ni] = (f32x4){0.f, 0.f, 0.f, 0.f};
        }

    for (int kq = 0; kq < 4; ++kq) {
        // ---- stage A quarter (128 rows x 128k bf16 = 32KB), swizzled ----
#pragma unroll
        for (int q = 0; q < 8; ++q) {
            int c = q * 256 + tid;
            int row = c >> 4, kk = c & 15;
            uint4 v = *(const uint4*)(hb + (size_t)(m0 + row) * KDIM + kq * 128 + kk * 8);
            *(uint4*)(As + row * 256 + ((kk ^ (row & 7)) << 4)) = v;
        }
        // ---- B chunk stage: 128 rows x 64k, pre-swizzled global src, linear dst
        auto stageB = [&](int buf, int p, int k0c) {
            int wrow = MODE ? (33280 + p * 256 + nh * 128)
                            : ((p - halfS * 65) * 512 + halfS * 256 + nh * 128);
            const int rsub = tid >> 3;                    // 0..31
            const int sl = (tid & 7) ^ (rsub & 7);        // inverse read-swizzle
            const unsigned short* src0 = Wb + (size_t)(wrow + rsub) * KDIM
                                       + kq * 128 + k0c * 64 + sl * 8;
            char* dst0 = Bs + buf * 16384 + tid * 16;     // wave-uniform + lane*16
#pragma unroll
            for (int q = 0; q < 4; ++q)
                gload_lds16(src0 + (size_t)q * 32 * KDIM, dst0 + q * 4096);
        };
        stageB(0, pBeg, 0);
        __syncthreads();                                   // full drain, once per kq
        int cur = 0;
        for (int p = pBeg; p < pEnd; ++p) {
#pragma unroll
            for (int k0 = 0; k0 < 2; ++k0) {
                const bool last = (p == pEnd - 1) && (k0 == 1);
                if (!last) {
                    stageB(cur ^ 1, k0 ? p + 1 : p, k0 ^ 1);   // 4 loads in flight
                    asm volatile("s_waitcnt vmcnt(4)" ::: "memory");  // cur ready
                } else {
                    asm volatile("s_waitcnt vmcnt(0)" ::: "memory");
                }
                __builtin_amdgcn_s_barrier();
                asm volatile("" ::: "memory");
                char* Bbuf = Bs + cur * 16384;
                __builtin_amdgcn_s_setprio(1);
#pragma unroll
                for (int ks = 0; ks < 2; ++ks) {
                    v8bf af[4], bfr[4];
                    const int sA = k0 * 8 + ks * 4 + lg;
                    const int sB = ks * 4 + lg;
#pragma unroll
                    for (int mi = 0; mi < 4; ++mi)
                        af[mi] = *(const v8bf*)(As + aB[mi] + ((sA ^ aX[mi]) << 4));
#pragma unroll
                    for (int ni = 0; ni < 4; ++ni)
                        bfr[ni] = *(const v8bf*)(Bbuf + bB[ni] + ((sB ^ bX[ni]) << 4));
#pragma unroll
                    for (int mi = 0; mi < 4; ++mi)
#pragma unroll
                        for (int ni = 0; ni < 4; ++ni)
                            accP[mi][ni] = __builtin_amdgcn_mfma_f32_16x16x32_bf16(
                                af[mi], bfr[ni], accP[mi][ni], 0, 0, 0);
                }
                __builtin_amdgcn_s_setprio(0);
                if (k0 == 1) {
                    // scale-accumulate P into O (vectorized over the 4 acc rows)
                    int jj = MODE ? ((p - pBeg) * 2 + wn) : (p - pBeg);
                    const f32x4* scv = (const f32x4*)(sc + jj * 128);
#pragma unroll
                    for (int mi = 0; mi < 4; ++mi) {
                        f32x4 sv = scv[wm * 16 + mi * 4 + lg];
#pragma unroll
                        for (int ni = 0; ni < 4; ++ni) {
                            accO[mi][ni] += sv * accP[mi][ni];
                            accP[mi][ni] = (f32x4){0.f, 0.f, 0.f, 0.f};
                        }
                    }
                }
                asm volatile("" ::: "memory");
                __builtin_amdgcn_s_barrier();
                cur ^= 1;
            }
        }
    }
    // ---- epilogue: atomic accumulate ----
#pragma unroll
    for (int mi = 0; mi < 4; ++mi)
#pragma unroll
        for (int ni = 0; ni < 4; ++ni)
#pragma unroll
            for (int r = 0; r < 4; ++r) {
                int row = wm * 64 + mi * 16 + lg * 4 + r;
                int col = MODE ? (ni * 16 + lr)
                               : (halfS * 256 + nh * 128 + wn * 64 + ni * 16 + lr);
                atomicAdd(outAcc + (size_t)(m0 + row) * OUTW + col, accO[mi][ni][r]);
            }
}

// ---------------- K3: y = elu(ypre + real·b_out[i*512+h'] + b_out[32768+h']) ----
__global__ void k_fin_y(const float* __restrict__ ypre, const float* __restrict__ x,
                        const float* __restrict__ b_out, float* __restrict__ y) {
    int idx = blockIdx.x * 256 + threadIdx.x;   // b*512 + hh
    int b = idx >> 9, hh = idx & 511;
    float acc = ypre[idx] + b_out[32768 + hh];
    const float* xr = x + (size_t)b * XW;       // real part
#pragma unroll 8
    for (int i = 0; i < 64; ++i)
        acc += xr[i] * b_out[i * 512 + hh];
    y[idx] = elu1(acc);
}

// ---------------- K5: out += y·b_out[33280+h'*64+o] + b_out[66048+o] ------------
__global__ void k_fin_out(const float* __restrict__ y, const float* __restrict__ b_out,
                          float* __restrict__ out) {
    int idx = blockIdx.x * 256 + threadIdx.x;   // b*64 + o
    int b = idx >> 6, o = idx & 63;
    float acc = out[idx] + b_out[66048 + o];
    const float* yr = y + (size_t)b * 512;
#pragma unroll 8
    for (int hh = 0; hh < 512; ++hh)
        acc += yr[hh] * b_out[33280 + hh * 64 + o];
    out[idx] = acc;
}

extern "C" void kernel_launch(void* const* d_in, const int* in_sizes, int n_in,
                              void* d_out, int out_size, void* d_ws, size_t ws_size,
                              hipStream_t stream) {
    const float* x     = (const float*)d_in[0];
    const float* W_in  = (const float*)d_in[1];
    const float* b_in  = (const float*)d_in[2];
    const float* W_out = (const float*)d_in[3];
    const float* b_out = (const float*)d_in[4];
    float* out = (float*)d_out;

    char* ws = (char*)d_ws;
    unsigned short* hb = (unsigned short*)ws;            // 2 MB  h bf16
    float* ypre        = (float*)(ws + (2u << 20));      // 4 MB
    float* yv          = (float*)(ws + (6u << 20));      // 4 MB
    unsigned short* Wb = (unsigned short*)(ws + (10u << 20));  // 68.2 MB bf16 W_out

    hipMemsetAsync(ypre, 0, (size_t)B_N * 512 * 4, stream);
    hipMemsetAsync(out,  0, (size_t)B_N * 64 * 4, stream);

    k_h<<<(B_N * 512) / 256, 256, 0, stream>>>(x, W_in, b_in, hb);
    k_conv<<<(NROWS_PAD * KDIM / 8) / 256, 256, 0, stream>>>(W_out, Wb);

    // Stage 2: y_pre = sum_i real_i * (h @ W_i^T)  (+ l_in_b panel, scale 1)
    k_pgemm<0><<<dim3(16, 2, 16), 256, 0, stream>>>(hb, Wb, x, ypre);

    k_fin_y<<<(B_N * 512) / 256, 256, 0, stream>>>(ypre, x, b_out, yv);

    // Stage 3: out = sum_h' y_h' * (h @ W2_h'^T)  (+ l_out_b panel, scale 1)
    k_pgemm<1><<<dim3(16, 2, 16), 256, 0, stream>>>(hb, Wb, yv, out);

    k_fin_out<<<(B_N * 64) / 256, 256, 0, stream>>>(yv, b_out, out);
}